// Round 11
// baseline (886.715 us; speedup 1.0000x reference)
//
#include <hip/hip_runtime.h>

typedef __bf16 bf16x8 __attribute__((ext_vector_type(8)));
typedef float  f32x4  __attribute__((ext_vector_type(4)));

__device__ __forceinline__ unsigned short f2bf(float x){
  return __builtin_bit_cast(unsigned short, (__bf16)x);   // HW v_cvt on gfx950, RNE
}

// LDS-only barrier: hazards are LDS ping-pong buffers; wait lgkmcnt only.
__device__ __forceinline__ void bar_lds(){
  asm volatile("s_waitcnt lgkmcnt(0)" ::: "memory");
  __builtin_amdgcn_s_barrier();
  asm volatile("" ::: "memory");
}

// ---------------------------------------------------------------------------
// Weight pack (unchanged from R9): B-frag order, gate weights pre-scaled by
// -log2(e) (i,f,o) / -2log2(e) (g). Sections: [0,48) encL0, [48,112) encL1,
// [112,160) decL0, [160,224) decL1, [224,226) W_out.
// ---------------------------------------------------------------------------
__global__ void pack_weights(const float* __restrict__ eWih0, const float* __restrict__ eWhh0,
                             const float* __restrict__ eWih1, const float* __restrict__ eWhh1,
                             const float* __restrict__ dWih0, const float* __restrict__ dWhh0,
                             const float* __restrict__ dWih1, const float* __restrict__ dWhh1,
                             const float* __restrict__ Wout,
                             unsigned short* __restrict__ out){
  int t = blockIdx.x * 256 + threadIdx.x;
  if (t >= 226 * 64) return;
  int lane = t & 63;
  int f    = t >> 6;
  unsigned short vals[8];
  if (f >= 224){                                       // W_out frags (NOT scaled)
    int kt = f - 224, n = lane & 15;
#pragma unroll
    for (int jj = 0; jj < 8; jj++){
      int k = kt * 32 + (lane >> 4) * 8 + jj;
      vals[jj] = (n < 4) ? f2bf(Wout[n * 64 + k]) : (unsigned short)0;
    }
  } else {
    const float *Wih, *Whh; int kx, ntile, kt;
    if (f < 48)       { Wih=eWih0; Whh=eWhh0; kx=16; ntile=f/3;        kt=f%3; }
    else if (f < 112) { Wih=eWih1; Whh=eWhh1; kx=64; ntile=(f-48)/4;   kt=(f-48)%4; }
    else if (f < 160) { Wih=dWih0; Whh=dWhh0; kx=16; ntile=(f-112)/3;  kt=(f-112)%3; }
    else              { Wih=dWih1; Whh=dWhh1; kx=64; ntile=(f-160)/4;  kt=(f-160)%4; }
    int n    = ntile * 16 + (lane & 15);
    int hoff = (kx == 16) ? 32 : 64;
    float scale = ((ntile >> 2) == 2) ? -2.88539008f : -1.44269504f;
#pragma unroll
    for (int jj = 0; jj < 8; jj++){
      int k = kt * 32 + (lane >> 4) * 8 + jj;
      float v;
      if (k < kx)        v = Wih[n * kx + k];
      else if (k < hoff) v = 0.0f;
      else               v = Whh[n * 64 + (k - hoff)];
      vals[jj] = f2bf(v * scale);
    }
  }
  uint4 o;
  o.x = (unsigned)vals[0] | ((unsigned)vals[1] << 16);
  o.y = (unsigned)vals[2] | ((unsigned)vals[3] << 16);
  o.z = (unsigned)vals[4] | ((unsigned)vals[5] << 16);
  o.w = (unsigned)vals[6] | ((unsigned)vals[7] << 16);
  ((uint4*)out)[f * 64 + lane] = o;
}

// A-layout (per 16-row subtile): elem(m,k) at ((k>>5)*64 + (m | (((k>>3)&3)<<4)))*8 + (k&7)
// Self-transpose: a bf16x8 read at (kt*64+lane)*8 is A-frag of tile AND B-frag of tile^T.
__device__ __forceinline__ void write_h(unsigned short* buf, int k, int quad,
                                        const unsigned short* h){
  unsigned short* p = buf + (((k >> 5) * 64) + quad * 4 + (((k >> 3) & 3) << 4)) * 8 + (k & 7);
#pragma unroll
  for (int e = 0; e < 4; e++) p[e * 8] = h[e];
}

// Wave-specialized weight load: W0 waves hold only their cell0 slice (12
// frags), W1 waves only cell1 (16 frags) — per-wave weight file 48/64 VGPR,
// enabling 4 waves/SIMD.
__device__ __forceinline__ void load_bw(const unsigned short* __restrict__ pw,
                                        bool isW0, int w4, int lane,
                                        int base0, int base1, bf16x8 (&BW)[4][4]){
  if (isW0){
#pragma unroll
    for (int g = 0; g < 4; g++)
#pragma unroll
      for (int kt = 0; kt < 3; kt++)
        BW[g][kt] = *(const bf16x8*)(pw + (((long)(base0 + (4*g + w4)*3 + kt)) * 64 + lane) * 8);
  } else {
#pragma unroll
    for (int g = 0; g < 4; g++)
#pragma unroll
      for (int kt = 0; kt < 4; kt++)
        BW[g][kt] = *(const bf16x8*)(pw + (((long)(base1 + (4*g + w4)*4 + kt)) * 64 + lane) * 8);
  }
}

// Activation epilogue (exp2-ready acc, single-rcp c-update):
//   c2 = [c*(1+ei)(1+eg) + K(1-eg)(1+ef)] / [(1+ef)(1+ei)(1+eg)],  K = 2*log2(e)
//   sig(o)*tanh(c) = (ec-1)/((1+eo)(1+ec)),  ec = exp2(c2)
__device__ __forceinline__ void cell_act(f32x4 (&acc)[4][2], float (&c)[8],
                                         unsigned short (&hout)[8]){
#pragma unroll
  for (int rt = 0; rt < 2; rt++){
#pragma unroll
    for (int e = 0; e < 4; e++){
      int idx = rt * 4 + e;
      float ei = __builtin_amdgcn_exp2f(acc[0][rt][e]);
      float ef = __builtin_amdgcn_exp2f(acc[1][rt][e]);
      float eg = __builtin_amdgcn_exp2f(acc[2][rt][e]);
      float eo = __builtin_amdgcn_exp2f(acc[3][rt][e]);
      float pf   = 1.0f + ef;
      float pig  = (1.0f + ei) * (1.0f + eg);
      float rden = __builtin_amdgcn_rcpf(pf * pig);
      float num  = fmaf(fmaf(-2.88539008f, eg, 2.88539008f), pf, c[idx] * pig);
      float c2   = num * rden;
      c[idx] = c2;
      float ec  = __builtin_amdgcn_exp2f(c2);
      float rot = __builtin_amdgcn_rcpf((1.0f + eo) * (1.0f + ec));
      hout[idx] = f2bf((ec - 1.0f) * rot);
    }
  }
}

// Partial cell: MFMA K-tiles [KT_LO, KT_HI) for both row-subtiles, optional
// bias init and activation. 8 independent MFMA chains.
template<int KT_LO, int KT_HI, int SZ, bool INIT, bool ACT>
__device__ __forceinline__ void cell_part(const unsigned short* __restrict__ A,
                                          const bf16x8 (&BW)[4][4],
                                          const float (&bias)[4],
                                          f32x4 (&acc)[4][2],
                                          float (&c)[8],
                                          unsigned short (&hout)[8],
                                          int lane){
  if constexpr (INIT){
#pragma unroll
    for (int g = 0; g < 4; g++){
      f32x4 b = {bias[g], bias[g], bias[g], bias[g]};
      acc[g][0] = b; acc[g][1] = b;
    }
  }
#pragma unroll
  for (int kt = KT_LO; kt < KT_HI; kt++){
    bf16x8 a0 = *(const bf16x8*)(A +      (kt * 64 + lane) * 8);
    bf16x8 a1 = *(const bf16x8*)(A + SZ + (kt * 64 + lane) * 8);
#pragma unroll
    for (int g = 0; g < 4; g++){
      acc[g][0] = __builtin_amdgcn_mfma_f32_16x16x32_bf16(a0, BW[g][kt], acc[g][0], 0, 0, 0);
      acc[g][1] = __builtin_amdgcn_mfma_f32_16x16x32_bf16(a1, BW[g][kt], acc[g][1], 0, 0, 0);
    }
  }
  if constexpr (ACT) cell_act(acc, c, hout);
}

// ---------------------------------------------------------------------------
// Main: one block = 32 batch rows, 512 threads = 8 waves, WAVE-SPECIALIZED:
// waves 0-3 (W0) own cell0 (+x-proj, projC), waves 4-7 (W1) own cell1.
// Per-wave weight file 48/64 VGPR -> 4 waves/SIMD (vs 2 unified) for latency
// hiding. Encoder: 1 bar/step, W0:cell0(t) || W1:cell1(t-1). Decoder: 3
// bars/step, segA {W0 cell0-finish+act || W1 cell1-start}, segB {W1 finish+act
// || W0 cell0-start(t+1)}, segC projC (MFMA-transposed, R9). c-state carries
// enc->dec per wave set (matches ref). All barriers LDS-only.
// ---------------------------------------------------------------------------
__global__ __launch_bounds__(512, 4)
void lstm_main(const float* __restrict__ src, const float* __restrict__ trg,
               const float* __restrict__ W_in, const float* __restrict__ b_in,
               const float* __restrict__ eb0, const float* __restrict__ eb1,
               const float* __restrict__ db0, const float* __restrict__ db1,
               const float* __restrict__ bout,
               const unsigned short* __restrict__ pw,
               float* __restrict__ out){
  __shared__ __align__(16) unsigned short A0[2][2][1536];   // ping-pong, 2 subtiles, K=96
  __shared__ __align__(16) unsigned short A1[2][2][2048];   // K=128
  __shared__ __align__(16) float xsrc[2][128];              // encoder x ping-pong
  __shared__ __align__(16) unsigned short sWoutF[1024];     // W_out frags (A/B-usable)
  __shared__ __align__(16) unsigned short sWinF[512];       // W_in A-frag (K=4 pad 32)

  const int tid  = threadIdx.x;
  const int lane = tid & 63;
  const int w    = tid >> 6;                  // 0..7
  const int w4   = w & 3;
  const bool isW0 = (w < 4);
  const int quad = lane >> 4;
  const int l16  = lane & 15;
  const int jj   = 16 * w4 + l16;             // j-slice within 64
  const int rowg0 = blockIdx.x * 32;
  const int mm   = tid & 15;                  // x-proj m-unit (tid<256)
  const int xr   = (tid >> 4) & 15;           // x-proj rows xr, xr+16 (tid<256)

  // ---- staging ----
  {
    uint4 z; z.x = z.y = z.z = z.w = 0u;
    uint4* a0p = (uint4*)A0;                  // 768 uint4
    uint4* a1p = (uint4*)A1;                  // 1024 uint4
    for (int i = tid; i < 768;  i += 512) a0p[i] = z;
    for (int i = tid; i < 1024; i += 512) a1p[i] = z;
    if (tid < 128) ((uint4*)sWoutF)[tid] = ((const uint4*)pw)[224 * 64 + tid];
    if (tid < 64){                            // W_in A-frag: lane<16, jj<4 = W_in[l][jj]
      unsigned short v[8] = {0,0,0,0,0,0,0,0};
      if (tid < 16){
#pragma unroll
        for (int q = 0; q < 4; q++) v[q] = f2bf(W_in[tid * 4 + q]);
      }
      uint4 o;
      o.x = (unsigned)v[0] | ((unsigned)v[1] << 16);
      o.y = (unsigned)v[2] | ((unsigned)v[3] << 16);
      o.z = o.w = 0u;
      ((uint4*)sWinF)[tid] = o;
    }
    if (tid < 128) xsrc[0][tid] = src[(long)(rowg0 + (tid >> 2)) * 256 + (tid & 3)];
  }
  const float4 wv = *(const float4*)&W_in[mm * 4];
  const float  bin = b_in[mm];

  bf16x8 BW[4][4];                            // W0: [g][kt<3]; W1: [g][kt<4]
  float bias[4];
  f32x4 acc[4][2];                            // W0: loop-carried accP; W1: cell1 acc
  float cc[8] = {0,0,0,0,0,0,0,0};            // c-state (W0: c0, W1: c1)
  unsigned short hr[8];

  load_bw(pw, isW0, w4, lane, 0, 48, BW);
#pragma unroll
  for (int g = 0; g < 4; g++){
    int n = 64*g + jj;
    float s = (g == 2) ? -2.88539008f : -1.44269504f;
    bias[g] = (isW0 ? eb0[n] : eb1[n]) * s;
  }
  bar_lds();

  const int xoff = (xr | ((mm >> 3) << 4)) * 8 + (mm & 7);   // A-layout slot for k=mm

  // ================= encoder: 1 barrier/step, W0||W1 =================
  for (int t = 0; t < 64; t++){
    int cur = t & 1, nxt = cur ^ 1;
    float xv;
    if (tid < 128)
      xv = src[(long)(rowg0 + (tid >> 2)) * 256 + ((t == 63 ? 63 : t + 1) << 2) + (tid & 3)];
    if (tid < 256){ // x-projection for rows xr, xr+16 (W0 threads)
      float4 x0 = *(const float4*)&xsrc[cur][xr * 4];
      float4 x1 = *(const float4*)&xsrc[cur][(xr + 16) * 4];
      float m0 = bin + x0.x*wv.x + x0.y*wv.y + x0.z*wv.z + x0.w*wv.w;
      float m1 = bin + x1.x*wv.x + x1.y*wv.y + x1.z*wv.z + x1.w*wv.w;
      A0[cur][0][xoff] = f2bf(m0);
      A0[cur][1][xoff] = f2bf(m1);
    }
    if (tid < 128) xsrc[nxt][tid] = xv;
    bar_lds();
    if (isW0){
      // cell0(t): x(t) + h0(t-1)
      cell_part<0, 3, 1536, true, true>(&A0[cur][0][0], BW, bias, acc, cc, hr, lane);
#pragma unroll
      for (int rt = 0; rt < 2; rt++){
        write_h(&A0[nxt][rt][0], 32 + jj, quad, hr + rt * 4);   // recurrent h0
        write_h(&A1[cur][rt][0],      jj, quad, hr + rt * 4);   // feed layer 1
      }
    } else if (t > 0){
      // cell1(t-1): h0(t-1) feed + h1(t-2) recurrent (both pre-barrier)
      cell_part<0, 4, 2048, true, true>(&A1[nxt][0][0], BW, bias, acc, cc, hr, lane);
#pragma unroll
      for (int rt = 0; rt < 2; rt++)
        write_h(&A1[cur][rt][0], 64 + jj, quad, hr + rt * 4);   // recurrent h1
    }
  }
  bar_lds();
  // phase switch: W1 flushes cell1(63); W0 loads decoder weights + prologue
  if (!isW0){
    cell_part<0, 4, 2048, true, true>(&A1[1][0][0], BW, bias, acc, cc, hr, lane);
#pragma unroll
    for (int rt = 0; rt < 2; rt++)
      write_h(&A1[0][rt][0], 64 + jj, quad, hr + rt * 4);       // h1 for dec t=0
  }
  load_bw(pw, isW0, w4, lane, 112, 160, BW);
#pragma unroll
  for (int g = 0; g < 4; g++){
    int n = 64*g + jj;
    float s = (g == 2) ? -2.88539008f : -1.44269504f;
    bias[g] = (isW0 ? db0[n] : db1[n]) * s;
  }
  const float4 bq = *(const float4*)&b_in[quad * 4];            // C-init of m^T
  f32x4 boT = {0.0f, 0.0f, 0.0f, 0.0f};
  if (quad == 0){
    float4 b4 = *(const float4*)bout;
    boT[0] = b4.x; boT[1] = b4.y; boT[2] = b4.z; boT[3] = b4.w;
  }
  if (tid < 256){ // m(0) = trg(:,0) @ W_in^T + b_in -> A0[0] m-slots
    float4 x0 = *(const float4*)&trg[(long)(rowg0 + xr) * 256];
    float4 x1 = *(const float4*)&trg[(long)(rowg0 + xr + 16) * 256];
    float m0 = bin + x0.x*wv.x + x0.y*wv.y + x0.z*wv.z + x0.w*wv.w;
    float m1 = bin + x1.x*wv.x + x1.y*wv.y + x1.z*wv.z + x1.w*wv.w;
    A0[0][0][xoff] = f2bf(m0);
    A0[0][1][xoff] = f2bf(m1);
  }
  if (isW0)     // accP prologue: cell0(0) kt1,2 from A0[0] h0 = h0_enc(63)
    cell_part<1, 3, 1536, true, false>(&A0[0][0][0], BW, bias, acc, cc, hr, lane);
  bar_lds();

  // ================= decoder: 3 barriers/step, specialized =================
  for (int t = 0; t < 64; t++){
    int cur = t & 1, nxt = cur ^ 1;
    float4 tpreT = {0.0f, 0.0f, 0.0f, 0.0f};
    // --- seg A: W0 cell0-finish(t) || W1 cell1-start(t) ---
    if (isW0){
      if (w < 2 && quad == 0)
        tpreT = *(const float4*)&trg[(long)(rowg0 + w * 16 + l16) * 256 + t * 4];
      cell_part<0, 1, 1536, false, true>(&A0[cur][0][0], BW, bias, acc, cc, hr, lane);
#pragma unroll
      for (int rt = 0; rt < 2; rt++){
        write_h(&A0[nxt][rt][0], 32 + jj, quad, hr + rt * 4);   // h0 for t+1
        write_h(&A1[cur][rt][0],      jj, quad, hr + rt * 4);   // feed layer 1
      }
    } else {
      // cell1(t) kt2,3: h1(t-1) recurrent (in A1[cur] since barNext)
      cell_part<2, 4, 2048, true, false>(&A1[cur][0][0], BW, bias, acc, cc, hr, lane);
    }
    bar_lds();                             // barB: h0(t) visible
    // --- seg B: W1 cell1-finish(t) || W0 cell0-start(t+1) ---
    if (isW0){
      cell_part<1, 3, 1536, true, false>(&A0[nxt][0][0], BW, bias, acc, cc, hr, lane);
    } else {
      cell_part<0, 2, 2048, false, true>(&A1[cur][0][0], BW, bias, acc, cc, hr, lane);
#pragma unroll
      for (int rt = 0; rt < 2; rt++)
        write_h(&A1[nxt][rt][0], 64 + jj, quad, hr + rt * 4);   // h1 recurrent + projC src
    }
    bar_lds();                             // barC: h1(t) visible
    // --- seg C: projC (W0 waves 0,1) ---
    if (isW0 && w < 2){
      const unsigned short* Ah = &A1[nxt][w][0];
      bf16x8 hb0 = *(const bf16x8*)(Ah + (2 * 64 + lane) * 8);  // h1^T B-frags
      bf16x8 hb1 = *(const bf16x8*)(Ah + (3 * 64 + lane) * 8);
      bf16x8 wa0 = *(const bf16x8*)(sWoutF + lane * 8);         // Wout as A-frag
      bf16x8 wa1 = *(const bf16x8*)(sWoutF + 512 + lane * 8);
      f32x4 po = boT;                                           // pred^T
      po = __builtin_amdgcn_mfma_f32_16x16x32_bf16(wa0, hb0, po, 0, 0, 0);
      po = __builtin_amdgcn_mfma_f32_16x16x32_bf16(wa1, hb1, po, 0, 0, 0);
      unsigned int xp0 = 0u, xp1 = 0u;
      if (quad == 0){
        float4 xv;
        xv.x = po[0] + tpreT.x;  xv.y = po[1] + tpreT.y;
        xv.z = po[2] + tpreT.z;  xv.w = po[3] + tpreT.w;
        *(float4*)&out[(long)(rowg0 + w * 16 + l16) * 256 + t * 4] = xv;
        xp0 = (unsigned)f2bf(xv.x) | ((unsigned)f2bf(xv.y) << 16);
        xp1 = (unsigned)f2bf(xv.z) | ((unsigned)f2bf(xv.w) << 16);
      }
      uint4 xb_u; xb_u.x = xp0; xb_u.y = xp1; xb_u.z = 0u; xb_u.w = 0u;
      bf16x8 xb = __builtin_bit_cast(bf16x8, xb_u);             // x^T B-frag (K=4 pad 32)
      bf16x8 wi = *(const bf16x8*)(sWinF + lane * 8);           // W_in as A-frag
      f32x4 pm = {bq.x, bq.y, bq.z, bq.w};                      // m^T = W_in @ x^T + b_in
      pm = __builtin_amdgcn_mfma_f32_16x16x32_bf16(wi, xb, pm, 0, 0, 0);
      unsigned int mp0 = (unsigned)f2bf(pm[0]) | ((unsigned)f2bf(pm[1]) << 16);
      unsigned int mp1 = (unsigned)f2bf(pm[2]) | ((unsigned)f2bf(pm[3]) << 16);
      uint2 mw; mw.x = mp0; mw.y = mp1;
      *(uint2*)&A0[nxt][w][(l16 | ((quad >> 1) << 4)) * 8 + (quad & 1) * 4] = mw;
    }
    bar_lds();                             // barNext: m(t+1) + h0(t) ready
  }
}

extern "C" void kernel_launch(void* const* d_in, const int* in_sizes, int n_in,
                              void* d_out, int out_size, void* d_ws, size_t ws_size,
                              hipStream_t stream){
  (void)n_in; (void)out_size; (void)ws_size;
  const float* src   = (const float*)d_in[0];
  const float* trg   = (const float*)d_in[1];
  const float* W_in  = (const float*)d_in[2];
  const float* b_in  = (const float*)d_in[3];
  const float* eWih0 = (const float*)d_in[4];
  const float* eWhh0 = (const float*)d_in[5];
  const float* eb0   = (const float*)d_in[6];
  const float* eWih1 = (const float*)d_in[7];
  const float* eWhh1 = (const float*)d_in[8];
  const float* eb1   = (const float*)d_in[9];
  const float* dWih0 = (const float*)d_in[10];
  const float* dWhh0 = (const float*)d_in[11];
  const float* db0   = (const float*)d_in[12];
  const float* dWih1 = (const float*)d_in[13];
  const float* dWhh1 = (const float*)d_in[14];
  const float* db1   = (const float*)d_in[15];
  const float* Wout  = (const float*)d_in[16];
  const float* bout  = (const float*)d_in[17];
  unsigned short* pw = (unsigned short*)d_ws;          // needs 231,424 bytes

  pack_weights<<<57, 256, 0, stream>>>(eWih0, eWhh0, eWih1, eWhh1,
                                       dWih0, dWhh0, dWih1, dWhh1, Wout, pw);

  int B    = in_sizes[0] / 256;                        // S*I = 256
  int nblk = B / 32;
  lstm_main<<<nblk, 512, 0, stream>>>(src, trg, W_in, b_in, eb0, eb1, db0, db1,
                                      bout, pw, (float*)d_out);
}

// Round 12
// 661.604 us; speedup vs baseline: 1.3403x; 1.3403x over previous
//
#include <hip/hip_runtime.h>

typedef __bf16 bf16x8 __attribute__((ext_vector_type(8)));
typedef float  f32x4  __attribute__((ext_vector_type(4)));

__device__ __forceinline__ unsigned short f2bf(float x){
  return __builtin_bit_cast(unsigned short, (__bf16)x);   // HW v_cvt on gfx950, RNE
}

// LDS-only barrier: hazards are LDS ping-pong buffers; wait lgkmcnt only.
__device__ __forceinline__ void bar_lds(){
  asm volatile("s_waitcnt lgkmcnt(0)" ::: "memory");
  __builtin_amdgcn_s_barrier();
  asm volatile("" ::: "memory");
}

// ---------------------------------------------------------------------------
// Weight pack (unchanged): B-frag order, gate weights pre-scaled by -log2(e)
// (i,f,o) / -2log2(e) (g). Sections: [0,48) encL0, [48,112) encL1,
// [112,160) decL0, [160,224) decL1, [224,226) W_out.
// ---------------------------------------------------------------------------
__global__ void pack_weights(const float* __restrict__ eWih0, const float* __restrict__ eWhh0,
                             const float* __restrict__ eWih1, const float* __restrict__ eWhh1,
                             const float* __restrict__ dWih0, const float* __restrict__ dWhh0,
                             const float* __restrict__ dWih1, const float* __restrict__ dWhh1,
                             const float* __restrict__ Wout,
                             unsigned short* __restrict__ out){
  int t = blockIdx.x * 256 + threadIdx.x;
  if (t >= 226 * 64) return;
  int lane = t & 63;
  int f    = t >> 6;
  unsigned short vals[8];
  if (f >= 224){                                       // W_out frags (NOT scaled)
    int kt = f - 224, n = lane & 15;
#pragma unroll
    for (int jj = 0; jj < 8; jj++){
      int k = kt * 32 + (lane >> 4) * 8 + jj;
      vals[jj] = (n < 4) ? f2bf(Wout[n * 64 + k]) : (unsigned short)0;
    }
  } else {
    const float *Wih, *Whh; int kx, ntile, kt;
    if (f < 48)       { Wih=eWih0; Whh=eWhh0; kx=16; ntile=f/3;        kt=f%3; }
    else if (f < 112) { Wih=eWih1; Whh=eWhh1; kx=64; ntile=(f-48)/4;   kt=(f-48)%4; }
    else if (f < 160) { Wih=dWih0; Whh=dWhh0; kx=16; ntile=(f-112)/3;  kt=(f-112)%3; }
    else              { Wih=dWih1; Whh=dWhh1; kx=64; ntile=(f-160)/4;  kt=(f-160)%4; }
    int n    = ntile * 16 + (lane & 15);
    int hoff = (kx == 16) ? 32 : 64;
    float scale = ((ntile >> 2) == 2) ? -2.88539008f : -1.44269504f;
#pragma unroll
    for (int jj = 0; jj < 8; jj++){
      int k = kt * 32 + (lane >> 4) * 8 + jj;
      float v;
      if (k < kx)        v = Wih[n * kx + k];
      else if (k < hoff) v = 0.0f;
      else               v = Whh[n * 64 + (k - hoff)];
      vals[jj] = f2bf(v * scale);
    }
  }
  uint4 o;
  o.x = (unsigned)vals[0] | ((unsigned)vals[1] << 16);
  o.y = (unsigned)vals[2] | ((unsigned)vals[3] << 16);
  o.z = (unsigned)vals[4] | ((unsigned)vals[5] << 16);
  o.w = (unsigned)vals[6] | ((unsigned)vals[7] << 16);
  ((uint4*)out)[f * 64 + lane] = o;
}

// A-layout (per 16-row subtile): elem(m,k) at ((k>>5)*64 + (m | (((k>>3)&3)<<4)))*8 + (k&7)
// Self-transpose: a bf16x8 read at (kt*64+lane)*8 is A-frag of tile AND B-frag of tile^T.
__device__ __forceinline__ void write_h(unsigned short* buf, int k, int quad,
                                        const unsigned short* h){
  unsigned short* p = buf + (((k >> 5) * 64) + quad * 4 + (((k >> 3) & 3) << 4)) * 8 + (k & 7);
#pragma unroll
  for (int e = 0; e < 4; e++) p[e * 8] = h[e];
}

// One K-tile MFMA for both row-subtiles (8 chains).
template<int SZ>
__device__ __forceinline__ void mfma_step(const unsigned short* __restrict__ A, int kt,
                                          bf16x8 b0, bf16x8 b1, bf16x8 b2, bf16x8 b3,
                                          f32x4 (&acc)[4][2], int lane){
  bf16x8 a0 = *(const bf16x8*)(A +      (kt * 64 + lane) * 8);
  bf16x8 a1 = *(const bf16x8*)(A + SZ + (kt * 64 + lane) * 8);
  acc[0][0] = __builtin_amdgcn_mfma_f32_16x16x32_bf16(a0, b0, acc[0][0], 0, 0, 0);
  acc[0][1] = __builtin_amdgcn_mfma_f32_16x16x32_bf16(a1, b0, acc[0][1], 0, 0, 0);
  acc[1][0] = __builtin_amdgcn_mfma_f32_16x16x32_bf16(a0, b1, acc[1][0], 0, 0, 0);
  acc[1][1] = __builtin_amdgcn_mfma_f32_16x16x32_bf16(a1, b1, acc[1][1], 0, 0, 0);
  acc[2][0] = __builtin_amdgcn_mfma_f32_16x16x32_bf16(a0, b2, acc[2][0], 0, 0, 0);
  acc[2][1] = __builtin_amdgcn_mfma_f32_16x16x32_bf16(a1, b2, acc[2][1], 0, 0, 0);
  acc[3][0] = __builtin_amdgcn_mfma_f32_16x16x32_bf16(a0, b3, acc[3][0], 0, 0, 0);
  acc[3][1] = __builtin_amdgcn_mfma_f32_16x16x32_bf16(a1, b3, acc[3][1], 0, 0, 0);
}

__device__ __forceinline__ void acc_init(f32x4 (&acc)[4][2], const float (&bias)[4]){
#pragma unroll
  for (int g = 0; g < 4; g++){
    f32x4 b = {bias[g], bias[g], bias[g], bias[g]};
    acc[g][0] = b; acc[g][1] = b;
  }
}

// LDS-streamed B frag for gate g, wave-slice w4.
__device__ __forceinline__ bf16x8 lds_b(const unsigned short* __restrict__ s, int g, int w4,
                                        int lane){
  return *(const bf16x8*)(s + (((4 * g + w4) * 64) + lane) * 8);
}

// Activation (exp2-ready acc, single-rcp c-update):
//   c2 = [c*(1+ei)(1+eg) + K(1-eg)(1+ef)] / [(1+ef)(1+ei)(1+eg)],  K = 2*log2(e)
//   sig(o)*tanh(c) = (ec-1)/((1+eo)(1+ec)),  ec = exp2(c2)
__device__ __forceinline__ void cell_act(f32x4 (&acc)[4][2], float (&c)[8],
                                         unsigned short (&hout)[8]){
#pragma unroll
  for (int rt = 0; rt < 2; rt++){
#pragma unroll
    for (int e = 0; e < 4; e++){
      int idx = rt * 4 + e;
      float ei = __builtin_amdgcn_exp2f(acc[0][rt][e]);
      float ef = __builtin_amdgcn_exp2f(acc[1][rt][e]);
      float eg = __builtin_amdgcn_exp2f(acc[2][rt][e]);
      float eo = __builtin_amdgcn_exp2f(acc[3][rt][e]);
      float pf   = 1.0f + ef;
      float pig  = (1.0f + ei) * (1.0f + eg);
      float rden = __builtin_amdgcn_rcpf(pf * pig);
      float num  = fmaf(fmaf(-2.88539008f, eg, 2.88539008f), pf, c[idx] * pig);
      float c2   = num * rden;
      c[idx] = c2;
      float ec  = __builtin_amdgcn_exp2f(c2);
      float rot = __builtin_amdgcn_rcpf((1.0f + eo) * (1.0f + ec));
      hout[idx] = f2bf((ec - 1.0f) * rot);
    }
  }
}

// ---------------------------------------------------------------------------
// Main: one block = 32 batch rows, 512 threads, wave-specialized (W0=cell0,
// W1=cell1). Register diet for 4 waves/SIMD: one K-tile of each cell's
// weights streamed from LDS (sB0k1/sB1k0, re-staged enc->dec); W_in/b_in/bout
// live in LDS (no loop-resident projC constants). Decoder fully overlapped:
// segA {W0 cell0-finish+act || W1 cell1-start(kt2,3)}, segB {W0
// cell0-start(t+1) || W1 cell1-finish+act}, segC projC (MFMA-transposed).
// ---------------------------------------------------------------------------
__global__ __launch_bounds__(512, 4)
void lstm_main(const float* __restrict__ src, const float* __restrict__ trg,
               const float* __restrict__ W_in, const float* __restrict__ b_in,
               const float* __restrict__ eb0, const float* __restrict__ eb1,
               const float* __restrict__ db0, const float* __restrict__ db1,
               const float* __restrict__ bout,
               const unsigned short* __restrict__ pw,
               float* __restrict__ out){
  __shared__ __align__(16) unsigned short A0[2][2][1536];   // ping-pong, 2 subtiles, K=96
  __shared__ __align__(16) unsigned short A1[2][2][2048];   // K=128
  __shared__ __align__(16) float xsrc[2][128];              // encoder x ping-pong
  __shared__ __align__(16) unsigned short sWoutF[1024];     // W_out frags (A/B-usable)
  __shared__ __align__(16) unsigned short sB0k1[8192];      // cell0 kt1 B-frags (16KB)
  __shared__ __align__(16) unsigned short sB1k0[8192];      // cell1 kt0 B-frags (16KB)
  __shared__ __align__(16) float sWin[64];                  // W_in (16x4)
  __shared__ __align__(16) float sBin[16];                  // b_in
  __shared__ __align__(16) float sBout[4];                  // b_out

  const int tid  = threadIdx.x;
  const int lane = tid & 63;
  const int w    = tid >> 6;                  // 0..7
  const int w4   = w & 3;
  const bool isW0 = (w < 4);
  const int quad = lane >> 4;
  const int l16  = lane & 15;
  const int jj   = 16 * w4 + l16;
  const int rowg0 = blockIdx.x * 32;
  const int mm   = tid & 15;                  // x-proj m-unit (tid<256)
  const int xr   = (tid >> 4) & 15;           // x-proj rows xr, xr+16 (tid<256)

  // ---- staging ----
  {
    uint4 z; z.x = z.y = z.z = z.w = 0u;
    uint4* a0p = (uint4*)A0;                  // 768 uint4
    uint4* a1p = (uint4*)A1;                  // 1024 uint4
    for (int i = tid; i < 768;  i += 512) a0p[i] = z;
    for (int i = tid; i < 1024; i += 512) a1p[i] = z;
    const uint4* pwq = (const uint4*)pw;
    if (tid < 128) ((uint4*)sWoutF)[tid] = pwq[224 * 64 + tid];
    for (int i = tid; i < 1024; i += 512)     // enc B0 kt1
      ((uint4*)sB0k1)[i] = pwq[((i >> 6) * 3 + 1) * 64 + (i & 63)];
    for (int i = tid; i < 1024; i += 512)     // enc B1 kt0
      ((uint4*)sB1k0)[i] = pwq[(48 + (i >> 6) * 4) * 64 + (i & 63)];
    if (tid < 64) sWin[tid]  = W_in[tid];
    if (tid < 16) sBin[tid]  = b_in[tid];
    if (tid < 4)  sBout[tid] = bout[tid];
    if (tid < 128) xsrc[0][tid] = src[(long)(rowg0 + (tid >> 2)) * 256 + (tid & 3)];
  }

  // register-resident weights: W0 kt{0,2} of cell0; W1 kt{1,2,3} of cell1
  bf16x8 BWr[4][3];
  float bias[4];
  f32x4 acc[4][2];                            // W0: carried accP (dec); W1: cell1 acc
  float cc[8] = {0,0,0,0,0,0,0,0};
  unsigned short hr[8];

  if (isW0){
#pragma unroll
    for (int g = 0; g < 4; g++){
      int nt = 4 * g + w4;
      BWr[g][0] = *(const bf16x8*)(pw + (((long)(nt * 3 + 0)) * 64 + lane) * 8);
      BWr[g][1] = *(const bf16x8*)(pw + (((long)(nt * 3 + 2)) * 64 + lane) * 8);
    }
  } else {
#pragma unroll
    for (int g = 0; g < 4; g++){
      int nt = 4 * g + w4;
#pragma unroll
      for (int kt = 1; kt < 4; kt++)
        BWr[g][kt-1] = *(const bf16x8*)(pw + (((long)(48 + nt * 4 + kt)) * 64 + lane) * 8);
    }
  }
#pragma unroll
  for (int g = 0; g < 4; g++){
    int n = 64*g + jj;
    float s = (g == 2) ? -2.88539008f : -1.44269504f;
    bias[g] = (isW0 ? eb0[n] : eb1[n]) * s;
  }
  bar_lds();

  const int xoff = (xr | ((mm >> 3) << 4)) * 8 + (mm & 7);

  // ================= encoder: 1 barrier/step, W0||W1 =================
  for (int t = 0; t < 64; t++){
    int cur = t & 1, nxt = cur ^ 1;
    float xv;
    if (tid < 128)
      xv = src[(long)(rowg0 + (tid >> 2)) * 256 + ((t == 63 ? 63 : t + 1) << 2) + (tid & 3)];
    if (tid < 256){ // x-projection (W0 threads); wv/bin from LDS (broadcast reads)
      float4 wv = *(const float4*)&sWin[mm * 4];
      float  bi = sBin[mm];
      float4 x0 = *(const float4*)&xsrc[cur][xr * 4];
      float4 x1 = *(const float4*)&xsrc[cur][(xr + 16) * 4];
      float m0 = bi + x0.x*wv.x + x0.y*wv.y + x0.z*wv.z + x0.w*wv.w;
      float m1 = bi + x1.x*wv.x + x1.y*wv.y + x1.z*wv.z + x1.w*wv.w;
      A0[cur][0][xoff] = f2bf(m0);
      A0[cur][1][xoff] = f2bf(m1);
    }
    if (tid < 128) xsrc[nxt][tid] = xv;
    bar_lds();
    if (isW0){
      acc_init(acc, bias);
      mfma_step<1536>(&A0[cur][0][0], 0, BWr[0][0], BWr[1][0], BWr[2][0], BWr[3][0], acc, lane);
      mfma_step<1536>(&A0[cur][0][0], 1, lds_b(sB0k1,0,w4,lane), lds_b(sB0k1,1,w4,lane),
                      lds_b(sB0k1,2,w4,lane), lds_b(sB0k1,3,w4,lane), acc, lane);
      mfma_step<1536>(&A0[cur][0][0], 2, BWr[0][1], BWr[1][1], BWr[2][1], BWr[3][1], acc, lane);
      cell_act(acc, cc, hr);
#pragma unroll
      for (int rt = 0; rt < 2; rt++){
        write_h(&A0[nxt][rt][0], 32 + jj, quad, hr + rt * 4);   // recurrent h0
        write_h(&A1[cur][rt][0],      jj, quad, hr + rt * 4);   // feed layer 1
      }
    } else if (t > 0){
      acc_init(acc, bias);
      mfma_step<2048>(&A1[nxt][0][0], 0, lds_b(sB1k0,0,w4,lane), lds_b(sB1k0,1,w4,lane),
                      lds_b(sB1k0,2,w4,lane), lds_b(sB1k0,3,w4,lane), acc, lane);
      mfma_step<2048>(&A1[nxt][0][0], 1, BWr[0][0], BWr[1][0], BWr[2][0], BWr[3][0], acc, lane);
      mfma_step<2048>(&A1[nxt][0][0], 2, BWr[0][1], BWr[1][1], BWr[2][1], BWr[3][1], acc, lane);
      mfma_step<2048>(&A1[nxt][0][0], 3, BWr[0][2], BWr[1][2], BWr[2][2], BWr[3][2], acc, lane);
      cell_act(acc, cc, hr);
#pragma unroll
      for (int rt = 0; rt < 2; rt++)
        write_h(&A1[cur][rt][0], 64 + jj, quad, hr + rt * 4);   // recurrent h1
    }
  }
  bar_lds();
  // phase switch: W1 flushes cell1(63) (uses enc sB1k0); W0 restages sB0k1 (dec)
  if (!isW0){
    acc_init(acc, bias);
    mfma_step<2048>(&A1[1][0][0], 0, lds_b(sB1k0,0,w4,lane), lds_b(sB1k0,1,w4,lane),
                    lds_b(sB1k0,2,w4,lane), lds_b(sB1k0,3,w4,lane), acc, lane);
    mfma_step<2048>(&A1[1][0][0], 1, BWr[0][0], BWr[1][0], BWr[2][0], BWr[3][0], acc, lane);
    mfma_step<2048>(&A1[1][0][0], 2, BWr[0][1], BWr[1][1], BWr[2][1], BWr[3][1], acc, lane);
    mfma_step<2048>(&A1[1][0][0], 3, BWr[0][2], BWr[1][2], BWr[2][2], BWr[3][2], acc, lane);
    cell_act(acc, cc, hr);
#pragma unroll
    for (int rt = 0; rt < 2; rt++)
      write_h(&A1[0][rt][0], 64 + jj, quad, hr + rt * 4);       // h1 for dec t=0
  } else {
    const uint4* pwq = (const uint4*)pw;
    for (int i = tid; i < 1024; i += 256)     // dec B0 kt1
      ((uint4*)sB0k1)[i] = pwq[(112 + (i >> 6) * 3 + 1) * 64 + (i & 63)];
  }
  bar_lds();
  {
    const uint4* pwq = (const uint4*)pw;
    for (int i = tid; i < 1024; i += 512)     // dec B1 kt0
      ((uint4*)sB1k0)[i] = pwq[(160 + (i >> 6) * 4) * 64 + (i & 63)];
  }
  // decoder register weights + biases
  if (isW0){
#pragma unroll
    for (int g = 0; g < 4; g++){
      int nt = 4 * g + w4;
      BWr[g][0] = *(const bf16x8*)(pw + (((long)(112 + nt * 3 + 0)) * 64 + lane) * 8);
      BWr[g][1] = *(const bf16x8*)(pw + (((long)(112 + nt * 3 + 2)) * 64 + lane) * 8);
    }
  } else {
#pragma unroll
    for (int g = 0; g < 4; g++){
      int nt = 4 * g + w4;
#pragma unroll
      for (int kt = 1; kt < 4; kt++)
        BWr[g][kt-1] = *(const bf16x8*)(pw + (((long)(160 + nt * 4 + kt)) * 64 + lane) * 8);
    }
  }
#pragma unroll
  for (int g = 0; g < 4; g++){
    int n = 64*g + jj;
    float s = (g == 2) ? -2.88539008f : -1.44269504f;
    bias[g] = (isW0 ? db0[n] : db1[n]) * s;
  }
  if (tid < 256){ // m(0) = trg(:,0) @ W_in^T + b_in -> A0[0] m-slots
    float4 wv = *(const float4*)&sWin[mm * 4];
    float  bi = sBin[mm];
    float4 x0 = *(const float4*)&trg[(long)(rowg0 + xr) * 256];
    float4 x1 = *(const float4*)&trg[(long)(rowg0 + xr + 16) * 256];
    float m0 = bi + x0.x*wv.x + x0.y*wv.y + x0.z*wv.z + x0.w*wv.w;
    float m1 = bi + x1.x*wv.x + x1.y*wv.y + x1.z*wv.z + x1.w*wv.w;
    A0[0][0][xoff] = f2bf(m0);
    A0[0][1][xoff] = f2bf(m1);
  }
  bar_lds();
  if (isW0){  // accP prologue: cell0(0) kt1,2 from A0[0] h0 = h0_enc(63)
    acc_init(acc, bias);
    mfma_step<1536>(&A0[0][0][0], 1, lds_b(sB0k1,0,w4,lane), lds_b(sB0k1,1,w4,lane),
                    lds_b(sB0k1,2,w4,lane), lds_b(sB0k1,3,w4,lane), acc, lane);
    mfma_step<1536>(&A0[0][0][0], 2, BWr[0][1], BWr[1][1], BWr[2][1], BWr[3][1], acc, lane);
  }

  // ================= decoder: 3 barriers/step, fully overlapped =================
  for (int t = 0; t < 64; t++){
    int cur = t & 1, nxt = cur ^ 1;
    float4 tpreT = {0.0f, 0.0f, 0.0f, 0.0f};
    // --- seg A ---
    if (isW0){
      if (w < 2 && quad == 0)
        tpreT = *(const float4*)&trg[(long)(rowg0 + w * 16 + l16) * 256 + t * 4];
      // finish cell0(t): kt0 (m from projC(t-1)) + act
      mfma_step<1536>(&A0[cur][0][0], 0, BWr[0][0], BWr[1][0], BWr[2][0], BWr[3][0], acc, lane);
      cell_act(acc, cc, hr);
#pragma unroll
      for (int rt = 0; rt < 2; rt++){
        write_h(&A0[nxt][rt][0], 32 + jj, quad, hr + rt * 4);   // h0 for t+1
        write_h(&A1[cur][rt][0],      jj, quad, hr + rt * 4);   // feed layer 1
      }
    } else {
      // start cell1(t): kt2,3 (h1(t-1) recurrent, visible since barNext)
      acc_init(acc, bias);
      mfma_step<2048>(&A1[cur][0][0], 2, BWr[0][1], BWr[1][1], BWr[2][1], BWr[3][1], acc, lane);
      mfma_step<2048>(&A1[cur][0][0], 3, BWr[0][2], BWr[1][2], BWr[2][2], BWr[3][2], acc, lane);
    }
    bar_lds();                             // barB: h0(t) visible
    // --- seg B ---
    if (isW0){
      // start cell0(t+1): kt1,2 read A0[nxt] h0 (written pre-barB)
      acc_init(acc, bias);
      mfma_step<1536>(&A0[nxt][0][0], 1, lds_b(sB0k1,0,w4,lane), lds_b(sB0k1,1,w4,lane),
                      lds_b(sB0k1,2,w4,lane), lds_b(sB0k1,3,w4,lane), acc, lane);
      mfma_step<1536>(&A0[nxt][0][0], 2, BWr[0][1], BWr[1][1], BWr[2][1], BWr[3][1], acc, lane);
    } else {
      // finish cell1(t): kt0 (LDS) + kt1, then act
      mfma_step<2048>(&A1[cur][0][0], 0, lds_b(sB1k0,0,w4,lane), lds_b(sB1k0,1,w4,lane),
                      lds_b(sB1k0,2,w4,lane), lds_b(sB1k0,3,w4,lane), acc, lane);
      mfma_step<2048>(&A1[cur][0][0], 1, BWr[0][0], BWr[1][0], BWr[2][0], BWr[3][0], acc, lane);
      cell_act(acc, cc, hr);
#pragma unroll
      for (int rt = 0; rt < 2; rt++)
        write_h(&A1[nxt][rt][0], 64 + jj, quad, hr + rt * 4);   // h1 recurrent + projC src
    }
    bar_lds();                             // barC: h1(t) visible
    // --- seg C: projC (W0 waves 0,1) ---
    if (isW0 && w < 2){
      const unsigned short* Ah = &A1[nxt][w][0];
      bf16x8 hb0 = *(const bf16x8*)(Ah + (2 * 64 + lane) * 8);  // h1^T B-frags
      bf16x8 hb1 = *(const bf16x8*)(Ah + (3 * 64 + lane) * 8);
      bf16x8 wa0 = *(const bf16x8*)(sWoutF + lane * 8);         // Wout as A-frag
      bf16x8 wa1 = *(const bf16x8*)(sWoutF + 512 + lane * 8);
      f32x4 po = {0.0f, 0.0f, 0.0f, 0.0f};
      if (quad == 0){ po[0]=sBout[0]; po[1]=sBout[1]; po[2]=sBout[2]; po[3]=sBout[3]; }
      po = __builtin_amdgcn_mfma_f32_16x16x32_bf16(wa0, hb0, po, 0, 0, 0);
      po = __builtin_amdgcn_mfma_f32_16x16x32_bf16(wa1, hb1, po, 0, 0, 0);
      unsigned int xp0 = 0u, xp1 = 0u;
      if (quad == 0){
        float4 xv;
        xv.x = po[0] + tpreT.x;  xv.y = po[1] + tpreT.y;
        xv.z = po[2] + tpreT.z;  xv.w = po[3] + tpreT.w;
        *(float4*)&out[(long)(rowg0 + w * 16 + l16) * 256 + t * 4] = xv;
        xp0 = (unsigned)f2bf(xv.x) | ((unsigned)f2bf(xv.y) << 16);
        xp1 = (unsigned)f2bf(xv.z) | ((unsigned)f2bf(xv.w) << 16);
      }
      uint4 xb_u; xb_u.x = xp0; xb_u.y = xp1; xb_u.z = 0u; xb_u.w = 0u;
      bf16x8 xb = __builtin_bit_cast(bf16x8, xb_u);             // x^T B-frag (K=4 pad 32)
      // W_in A-frag rebuilt from LDS (lane<16 rows, else 0)
      uint4 wi_u; wi_u.x = wi_u.y = wi_u.z = wi_u.w = 0u;
      if (lane < 16){
        wi_u.x = (unsigned)f2bf(sWin[lane*4+0]) | ((unsigned)f2bf(sWin[lane*4+1]) << 16);
        wi_u.y = (unsigned)f2bf(sWin[lane*4+2]) | ((unsigned)f2bf(sWin[lane*4+3]) << 16);
      }
      bf16x8 wi = __builtin_bit_cast(bf16x8, wi_u);
      f32x4 pm = {sBin[quad*4+0], sBin[quad*4+1], sBin[quad*4+2], sBin[quad*4+3]};
      pm = __builtin_amdgcn_mfma_f32_16x16x32_bf16(wi, xb, pm, 0, 0, 0);
      unsigned int mp0 = (unsigned)f2bf(pm[0]) | ((unsigned)f2bf(pm[1]) << 16);
      unsigned int mp1 = (unsigned)f2bf(pm[2]) | ((unsigned)f2bf(pm[3]) << 16);
      uint2 mw; mw.x = mp0; mw.y = mp1;
      *(uint2*)&A0[nxt][w][(l16 | ((quad >> 1) << 4)) * 8 + (quad & 1) * 4] = mw;
    }
    bar_lds();                             // barNext: m(t+1) + h0(t) ready
  }
}

extern "C" void kernel_launch(void* const* d_in, const int* in_sizes, int n_in,
                              void* d_out, int out_size, void* d_ws, size_t ws_size,
                              hipStream_t stream){
  (void)n_in; (void)out_size; (void)ws_size;
  const float* src   = (const float*)d_in[0];
  const float* trg   = (const float*)d_in[1];
  const float* W_in  = (const float*)d_in[2];
  const float* b_in  = (const float*)d_in[3];
  const float* eWih0 = (const float*)d_in[4];
  const float* eWhh0 = (const float*)d_in[5];
  const float* eb0   = (const float*)d_in[6];
  const float* eWih1 = (const float*)d_in[7];
  const float* eWhh1 = (const float*)d_in[8];
  const float* eb1   = (const float*)d_in[9];
  const float* dWih0 = (const float*)d_in[10];
  const float* dWhh0 = (const float*)d_in[11];
  const float* db0   = (const float*)d_in[12];
  const float* dWih1 = (const float*)d_in[13];
  const float* dWhh1 = (const float*)d_in[14];
  const float* db1   = (const float*)d_in[15];
  const float* Wout  = (const float*)d_in[16];
  const float* bout  = (const float*)d_in[17];
  unsigned short* pw = (unsigned short*)d_ws;          // needs 231,424 bytes

  pack_weights<<<57, 256, 0, stream>>>(eWih0, eWhh0, eWih1, eWhh1,
                                       dWih0, dWhh0, dWih1, dWhh1, Wout, pw);

  int B    = in_sizes[0] / 256;                        // S*I = 256
  int nblk = B / 32;
  lstm_main<<<nblk, 512, 0, stream>>>(src, trg, W_in, b_in, eb0, eb1, db0, db1,
                                      bout, pw, (float*)d_out);
}